// Round 6
// baseline (275.790 us; speedup 1.0000x reference)
//
#include <hip/hip_runtime.h>

#define N_SAMP 1024
#define XC_DIM 512
#define YC_DIM 256
#define HID_DIM 512

typedef float float4n __attribute__((ext_vector_type(4)));  // native vec for nontemporal builtins

// ---------------------------------------------------------------------------
// K1: fused spatial pooling, coalesced + LDS transpose.
// sched_barrier(0) between load loop and consume loop forces all 16
// global_load_dwordx4 to issue before any use (r1-r4 the scheduler pipelined
// down to ~4 outstanding; VGPR_Count 32 proved it). Nontemporal: x,y are
// read exactly once.
// ---------------------------------------------------------------------------
__global__ __launch_bounds__(256, 2) void pool_kernel(
    const float* __restrict__ x, const float* __restrict__ y,
    float* __restrict__ x_vec, float* __restrict__ y_vec) {
  __shared__ float s[256 * 17];
  const int t = threadIdx.x;
  const long blk = blockIdx.x;
  const float4n* src;
  float* dst;
  long obase;
  if (blk < 2048) {            // x: 524288 outputs = 2048 blocks
    src = (const float4n*)x; dst = x_vec; obase = blk * 256;
  } else {                     // y: 262144 outputs = 1024 blocks
    src = (const float4n*)y; dst = y_vec; obase = (blk - 2048) * 256;
  }
  const float4n* p = src + obase * 16;

  float4n v[16];
#pragma unroll
  for (int k = 0; k < 16; ++k) v[k] = __builtin_nontemporal_load(&p[k * 256 + t]);
  __builtin_amdgcn_sched_barrier(0);  // all 16 loads in flight before any use

#pragma unroll
  for (int k = 0; k < 16; ++k) {
    float sv = (v[k].x + v[k].y) + (v[k].z + v[k].w);
    const int o = k * 16 + (t >> 4);
    const int j = t & 15;
    s[o * 17 + j] = sv;
  }
  __syncthreads();
  float acc = 0.f;
#pragma unroll
  for (int j = 0; j < 16; ++j) acc += s[t * 17 + j];
  dst[obase + t] = acc * (1.0f / 64.0f);
}

// ---------------------------------------------------------------------------
// K2: Hp[s] = x_vec @ W1[k-chunk s]. 64x64 tile, 4x4/thread, BK=16,
// splitK=4 (chunk 128 = 8 iters) -> grid (8,16,4) = 512 blocks.
// ---------------------------------------------------------------------------
#define TBK 16

__global__ __launch_bounds__(256) void gemm1_kernel(
    const float* __restrict__ A, const float* __restrict__ B,
    float* __restrict__ Hp) {
  const int K = 512, Nn = 512;
  __shared__ float As[TBK][68];
  __shared__ float Bs[TBK][68];
  const int t = threadIdx.x;
  const int bn = blockIdx.x * 64;
  const int bm = blockIdx.y * 64;
  const int ks = blockIdx.z;          // 0..3, K-chunk of 128

  const int arow = t >> 2, acol = (t & 3) * 4;
  const int brow = t >> 4, bcol = (t & 15) * 4;
  const int row0 = (t >> 4) * 4, col0 = (t & 15) * 4;

  float acc[4][4] = {};
  const int k0 = ks * 128;

  float4 av = *(const float4*)&A[(bm + arow) * K + k0 + acol];
  float4 bv = *(const float4*)&B[(k0 + brow) * Nn + bn + bcol];

  for (int it = 0; it < 8; ++it) {
    __syncthreads();
    As[acol + 0][arow] = av.x;
    As[acol + 1][arow] = av.y;
    As[acol + 2][arow] = av.z;
    As[acol + 3][arow] = av.w;
    *(float4*)&Bs[brow][bcol] = bv;
    __syncthreads();
    if (it < 7) {
      const int k1 = k0 + (it + 1) * TBK;
      av = *(const float4*)&A[(bm + arow) * K + k1 + acol];
      bv = *(const float4*)&B[(k1 + brow) * Nn + bn + bcol];
    }
#pragma unroll
    for (int kk = 0; kk < TBK; ++kk) {
      float4 a = *(const float4*)&As[kk][row0];
      float4 b = *(const float4*)&Bs[kk][col0];
      acc[0][0] += a.x * b.x; acc[0][1] += a.x * b.y; acc[0][2] += a.x * b.z; acc[0][3] += a.x * b.w;
      acc[1][0] += a.y * b.x; acc[1][1] += a.y * b.y; acc[1][2] += a.y * b.z; acc[1][3] += a.y * b.w;
      acc[2][0] += a.z * b.x; acc[2][1] += a.z * b.y; acc[2][2] += a.z * b.z; acc[2][3] += a.z * b.w;
      acc[3][0] += a.w * b.x; acc[3][1] += a.w * b.y; acc[3][2] += a.w * b.z; acc[3][3] += a.w * b.w;
    }
  }

  float* H = Hp + (long)ks * (N_SAMP * HID_DIM);
#pragma unroll
  for (int i = 0; i < 4; ++i) {
    float4 o;
    o.x = acc[i][0]; o.y = acc[i][1]; o.z = acc[i][2]; o.w = acc[i][3];
    *(float4*)&H[(long)(bm + row0 + i) * Nn + bn + col0] = o;
  }
}

// ---------------------------------------------------------------------------
// K3: part = relu(sum Hp + b1) @ W2[k-chunk]; FUSED epilogue accumulates
// dot += part.*y, colsum_mu[d] += part, and (ks==0 only) colsum_y[d] += y.
// mu partials never touch memory. b2's closed-form contribution is applied
// in finalize. grid (4,16,8) = 512 blocks.
// ---------------------------------------------------------------------------
__global__ __launch_bounds__(256) void gemm2_kernel(
    const float* __restrict__ Hp, const float* __restrict__ b1,
    const float* __restrict__ B, const float* __restrict__ yvec,
    float* __restrict__ colsum_mu, float* __restrict__ colsum_y,
    float* __restrict__ dot_out) {
  const int K = 512, Nn = 256;
  __shared__ float As[TBK][68];
  __shared__ float Bs[TBK][68];
  __shared__ float s_cm[64];
  __shared__ float s_cy[64];
  const int t = threadIdx.x;
  const int bn = blockIdx.x * 64;
  const int bm = blockIdx.y * 64;
  const int ks = blockIdx.z;          // 0..7, K-chunk of 64
  const long HS = (long)N_SAMP * HID_DIM;

  const int arow = t >> 2, acol = (t & 3) * 4;
  const int brow = t >> 4, bcol = (t & 15) * 4;
  const int row0 = (t >> 4) * 4, col0 = (t & 15) * 4;

  if (t < 64) { s_cm[t] = 0.f; s_cy[t] = 0.f; }

  float acc[4][4] = {};
  const int k0 = ks * 64;

  long aidx = (long)(bm + arow) * K + k0 + acol;
  float4 a0 = *(const float4*)&Hp[aidx];
  float4 a1 = *(const float4*)&Hp[aidx + HS];
  float4 a2 = *(const float4*)&Hp[aidx + 2 * HS];
  float4 a3 = *(const float4*)&Hp[aidx + 3 * HS];
  float4 bb = *(const float4*)&b1[k0 + acol];
  float4 bv = *(const float4*)&B[(k0 + brow) * Nn + bn + bcol];

  for (int it = 0; it < 4; ++it) {
    float4 av;
    av.x = fmaxf(a0.x + a1.x + a2.x + a3.x + bb.x, 0.0f);
    av.y = fmaxf(a0.y + a1.y + a2.y + a3.y + bb.y, 0.0f);
    av.z = fmaxf(a0.z + a1.z + a2.z + a3.z + bb.z, 0.0f);
    av.w = fmaxf(a0.w + a1.w + a2.w + a3.w + bb.w, 0.0f);
    __syncthreads();
    As[acol + 0][arow] = av.x;
    As[acol + 1][arow] = av.y;
    As[acol + 2][arow] = av.z;
    As[acol + 3][arow] = av.w;
    *(float4*)&Bs[brow][bcol] = bv;
    __syncthreads();
    if (it < 3) {
      const int k1 = k0 + (it + 1) * TBK;
      aidx = (long)(bm + arow) * K + k1 + acol;
      a0 = *(const float4*)&Hp[aidx];
      a1 = *(const float4*)&Hp[aidx + HS];
      a2 = *(const float4*)&Hp[aidx + 2 * HS];
      a3 = *(const float4*)&Hp[aidx + 3 * HS];
      bb = *(const float4*)&b1[k1 + acol];
      bv = *(const float4*)&B[(k1 + brow) * Nn + bn + bcol];
    }
#pragma unroll
    for (int kk = 0; kk < TBK; ++kk) {
      float4 a = *(const float4*)&As[kk][row0];
      float4 b = *(const float4*)&Bs[kk][col0];
      acc[0][0] += a.x * b.x; acc[0][1] += a.x * b.y; acc[0][2] += a.x * b.z; acc[0][3] += a.x * b.w;
      acc[1][0] += a.y * b.x; acc[1][1] += a.y * b.y; acc[1][2] += a.y * b.z; acc[1][3] += a.y * b.w;
      acc[2][0] += a.z * b.x; acc[2][1] += a.z * b.y; acc[2][2] += a.z * b.z; acc[2][3] += a.z * b.w;
      acc[3][0] += a.w * b.x; acc[3][1] += a.w * b.y; acc[3][2] += a.w * b.z; acc[3][3] += a.w * b.w;
    }
  }

  // Fused epilogue: dot, colsum_mu (this ks-part), colsum_y (ks==0 only).
  float dp = 0.f;
  float cm[4] = {};
  float cy[4] = {};
#pragma unroll
  for (int i = 0; i < 4; ++i) {
    float4 yv4 = *(const float4*)&yvec[(long)(bm + row0 + i) * Nn + bn + col0];
    dp += acc[i][0] * yv4.x + acc[i][1] * yv4.y + acc[i][2] * yv4.z + acc[i][3] * yv4.w;
    cm[0] += acc[i][0]; cm[1] += acc[i][1]; cm[2] += acc[i][2]; cm[3] += acc[i][3];
    cy[0] += yv4.x; cy[1] += yv4.y; cy[2] += yv4.z; cy[3] += yv4.w;
  }
  __syncthreads();  // s_cm/s_cy init + LDS tile reuse done
#pragma unroll
  for (int c = 0; c < 4; ++c) atomicAdd(&s_cm[col0 + c], cm[c]);
  if (ks == 0) {
#pragma unroll
    for (int c = 0; c < 4; ++c) atomicAdd(&s_cy[col0 + c], cy[c]);
  }
#pragma unroll
  for (int off = 1; off < 64; off <<= 1) dp += __shfl_xor(dp, off);
  if ((t & 63) == 0) atomicAdd(dot_out, dp);
  __syncthreads();
  if (t < 64) {
    atomicAdd(&colsum_mu[bn + t], s_cm[t]);
    if (ks == 0) atomicAdd(&colsum_y[bn + t], s_cy[t]);
  }
}

// ---------------------------------------------------------------------------
// K4: apply b2 closed-form and finish.
// dot_total   = dotp + sum_d b2[d]*colsum_y[d]
// cm_final[d] = colsum_mu[d] + N*b2[d]
// out = dot_total/N - (1/N^2) sum_d colsum_y[d]*cm_final[d]
// ---------------------------------------------------------------------------
__global__ __launch_bounds__(256) void finalize_kernel(
    const float* __restrict__ colsum_mu, const float* __restrict__ colsum_y,
    const float* __restrict__ b2, const float* __restrict__ dot_in,
    float* __restrict__ out) {
  __shared__ float p1[4], p2[4];
  const int t = threadIdx.x;  // d = t, 256 cols
  const float cy = colsum_y[t];
  const float bb = b2[t];
  float v1 = bb * cy;                                  // dot correction
  float v2 = cy * (colsum_mu[t] + 1024.0f * bb);       // colsum product
#pragma unroll
  for (int off = 1; off < 64; off <<= 1) {
    v1 += __shfl_xor(v1, off);
    v2 += __shfl_xor(v2, off);
  }
  if ((t & 63) == 0) { p1[t >> 6] = v1; p2[t >> 6] = v2; }
  __syncthreads();
  if (t == 0) {
    float s1 = p1[0] + p1[1] + p1[2] + p1[3];
    float s2 = p2[0] + p2[1] + p2[2] + p2[3];
    out[0] = (dot_in[0] + s1) * (1.0f / 1024.0f) - s2 * (1.0f / (1024.0f * 1024.0f));
  }
}

// ---------------------------------------------------------------------------
extern "C" void kernel_launch(void* const* d_in, const int* in_sizes, int n_in,
                              void* d_out, int out_size, void* d_ws, size_t ws_size,
                              hipStream_t stream) {
  const float* x  = (const float*)d_in[0];
  const float* y  = (const float*)d_in[1];
  const float* W1 = (const float*)d_in[2];
  const float* b1 = (const float*)d_in[3];
  const float* W2 = (const float*)d_in[4];
  const float* b2 = (const float*)d_in[5];
  float* out = (float*)d_out;

  char* ws = (char*)d_ws;
  float* x_vec = (float*)ws;                    // 2 MB
  float* y_vec = (float*)(ws + (2lu << 20));    // 1 MB
  float* Hp    = (float*)(ws + (4lu << 20));    // 4 x 2 MB = 8 MB
  float* accum = (float*)(ws + (12lu << 20));
  float* colsum_mu = accum;
  float* colsum_y  = accum + 256;
  float* dotp      = accum + 512;

  (void)hipMemsetAsync(accum, 0, 513 * sizeof(float), stream);

  pool_kernel<<<3072, 256, 0, stream>>>(x, y, x_vec, y_vec);

  gemm1_kernel<<<dim3(8, 16, 4), 256, 0, stream>>>(x_vec, W1, Hp);

  gemm2_kernel<<<dim3(4, 16, 8), 256, 0, stream>>>(Hp, b1, W2, y_vec,
                                                   colsum_mu, colsum_y, dotp);

  finalize_kernel<<<1, 256, 0, stream>>>(colsum_mu, colsum_y, b2, dotp, out);
}